// Round 6
// baseline (202.353 us; speedup 1.0000x reference)
//
#include <hip/hip_runtime.h>

constexpr int Bb = 8;
constexpr int Nn = 2048;
constexpr int Cc = 64;
constexpr int CAPS = 192;

typedef __attribute__((ext_vector_type(4))) float f32x4;
typedef __attribute__((ext_vector_type(16))) float f32x16;
typedef __attribute__((ext_vector_type(8))) short bf16x8;
typedef __attribute__((ext_vector_type(4))) unsigned u32x4;

__device__ inline unsigned short f2bf(float f){
  unsigned u = __builtin_bit_cast(unsigned, f);
  unsigned r = (u + 0x7FFFu + ((u>>16)&1u)) >> 16;
  return (unsigned short)r;
}
__device__ inline float bf2f(unsigned short h){
  unsigned u = ((unsigned)h)<<16; return __builtin_bit_cast(float,u);
}
__device__ inline unsigned pk2(float a, float b){
  return (unsigned)f2bf(a) | ((unsigned)f2bf(b)<<16);
}

#define MFMA32(a,b,c) __builtin_amdgcn_mfma_f32_32x32x16_bf16(a,b,c,0,0,0)

// ===== mega pre-kernel: prep(QK hi/lo + xt + xsum partials) | extract | WvT | zero Z =====
__global__ __launch_bounds__(256) void mega_k(
    const float* __restrict__ x, const float* __restrict__ A,
    const float* __restrict__ Wq, const float* __restrict__ Wk,
    const float* __restrict__ Tw, const float* __restrict__ Wv,
    unsigned short* __restrict__ Qhi, unsigned short* __restrict__ Qlo,
    unsigned short* __restrict__ Khi, unsigned short* __restrict__ Klo,
    float* __restrict__ xt, float* __restrict__ Xp,
    float* __restrict__ r_, float* __restrict__ diagA, int* __restrict__ cnt,
    int* __restrict__ idx, float* __restrict__ val,
    float* __restrict__ WvT, char* __restrict__ zerobase){
  __shared__ __attribute__((aligned(16))) char smem[65792];
  int blk = blockIdx.x; int t = threadIdx.x;

  if(blk < 256){
    // ---------------- prep ----------------
    float* wql = (float*)smem;           // 4096 f
    float* wkl = wql + 4096;
    float* twl = wkl + 4096;
    float (*xr)[64] = (float(*)[64])(twl + 4096); // [64][64]
    float* xsl = (float*)(xr + 64);      // 64 f
    #pragma unroll
    for(int i=0;i<4;i++){
      *(f32x4*)&wql[i*1024+t*4] = *(const f32x4*)&Wq[i*1024+t*4];
      *(f32x4*)&wkl[i*1024+t*4] = *(const f32x4*)&Wk[i*1024+t*4];
      *(f32x4*)&twl[i*1024+t*4] = *(const f32x4*)&Tw[i*1024+t*4];
    }
    if(t<64) xsl[t]=0.f;
    long long row0 = (long long)blk*64;
    int r = t>>4, q = t&15, c0 = q*4;
    #pragma unroll
    for(int i=0;i<4;i++){
      int row = i*16 + r;
      *(f32x4*)&xr[row][c0] = *(const f32x4*)&x[(row0+row)*Cc + c0];
    }
    __syncthreads();
    f32x4 aq[4], ak[4], at4[4];
    #pragma unroll
    for(int g=0;g<4;g++){ aq[g]=(f32x4){0,0,0,0}; ak[g]=(f32x4){0,0,0,0}; at4[g]=(f32x4){0,0,0,0}; }
    for(int kk=0;kk<64;kk++){
      f32x4 wq4 = *(const f32x4*)&wql[kk*64+c0];
      f32x4 wk4 = *(const f32x4*)&wkl[kk*64+c0];
      f32x4 wt4 = *(const f32x4*)&twl[kk*64+c0];
      #pragma unroll
      for(int g=0;g<4;g++){
        float xv = xr[g*16+r][kk];
        aq[g] += xv*wq4; ak[g] += xv*wk4; at4[g] += xv*wt4;
      }
    }
    float xsp[4] = {0.f,0.f,0.f,0.f};
    #pragma unroll
    for(int g=0;g<4;g++){
      #pragma unroll
      for(int d=0;d<4;d++) xsp[d] += xr[g*16+r][c0+d];
      long long g2 = (row0 + g*16 + r)*Cc + c0;
      unsigned long long hq=0,lq=0,hk=0,lk=0;
      #pragma unroll
      for(int d=0;d<4;d++){
        float v = aq[g][d];
        unsigned short h = f2bf(v); unsigned short lo2 = f2bf(v - bf2f(h));
        hq |= (unsigned long long)h << (16*d); lq |= (unsigned long long)lo2 << (16*d);
        v = ak[g][d];
        h = f2bf(v); lo2 = f2bf(v - bf2f(h));
        hk |= (unsigned long long)h << (16*d); lk |= (unsigned long long)lo2 << (16*d);
      }
      *(unsigned long long*)&Qhi[g2] = hq;
      *(unsigned long long*)&Qlo[g2] = lq;
      *(unsigned long long*)&Khi[g2] = hk;
      *(unsigned long long*)&Klo[g2] = lk;
      *(f32x4*)&xt[g2] = at4[g];
    }
    __syncthreads();
    #pragma unroll
    for(int d=0;d<4;d++) atomicAdd(&xsl[c0+d], xsp[d]);
    __syncthreads();
    if(t<64) Xp[blk*64+t] = xsl[t];
  } else if(blk < 768){
    // ---------------- extract ----------------
    int n = (blk-256)*4 + (t>>6); int l = t&63;
    const float* row = A + (size_t)n*Nn;
    float mn = 1e30f;
    for(int j=l;j<Nn;j+=64) mn = fminf(mn, row[j]);
    #pragma unroll
    for(int off=32;off>=1;off>>=1) mn = fminf(mn, __shfl_xor(mn,off));
    float thr = mn*1.3f;
    int bse=0;
    for(int j0=0;j0<Nn;j0+=64){
      float v = row[j0+l];
      bool f = v>thr;
      unsigned long long m = __ballot(f);
      int pos = __popcll(m & ((1ull<<l)-1ull));
      if(f && bse+pos<CAPS){ idx[n*CAPS+bse+pos]=j0+l; val[n*CAPS+bse+pos]=v-mn; }
      bse += __popcll(m);
    }
    if(l==0){ r_[n]=mn; diagA[n]=row[n]; cnt[n] = bse<CAPS? bse : CAPS; }
  } else if(blk < 800){
    // ---------------- WvT ----------------
    float (*tile)[65] = (float(*)[65])smem;
    int n0 = (blk-768)*64;
    for(int i=0;i<16;i++){
      int cc = i*4 + (t>>6); int nn2 = t&63;
      tile[cc][nn2] = Wv[(size_t)cc*Nn + n0 + nn2];
    }
    __syncthreads();
    for(int i=0;i<16;i++){
      int nn2 = i*4 + (t>>6); int cc = t&63;
      WvT[(size_t)(n0+nn2)*Cc + cc] = tile[cc][nn2];
    }
  } else {
    // ---------------- zero Z (64 KB, 1 block) ----------------
    char* dst = zerobase;
    uint4 zz = {0,0,0,0};
    #pragma unroll
    for(int i=0;i<16;i++) *(uint4*)(dst + ((size_t)i*256 + t)*16) = zz;
  }
}

// ===== zpass: Z[b][m] = sum_j exp(Q[b,j]·K[b,m])  (no E materialization) =====
__global__ __launch_bounds__(256) void zpass_k(
    const unsigned short* __restrict__ Qhi, const unsigned short* __restrict__ Qlo,
    const unsigned short* __restrict__ Khi, const unsigned short* __restrict__ Klo,
    float* __restrict__ Z){
  int t = threadIdx.x, w = t>>6, l = t&63, lr = l&31, hh = l>>5;
  int b = blockIdx.z;
  int j0 = blockIdx.x*128 + (w>>1)*64;
  int m0 = blockIdx.y*128 + (w&1)*64;
  const unsigned short* qb  = Qhi + ((size_t)b*Nn + j0 + lr)*Cc + hh*8;
  const unsigned short* qlb = Qlo + ((size_t)b*Nn + j0 + lr)*Cc + hh*8;
  const unsigned short* kb  = Khi + ((size_t)b*Nn + m0 + lr)*Cc + hh*8;
  const unsigned short* klb = Klo + ((size_t)b*Nn + m0 + lr)*Cc + hh*8;
  #pragma unroll
  for(int mm=0; mm<2; mm++){
    bf16x8 Bh[4], Bl[4];
    #pragma unroll
    for(int s=0;s<4;s++){
      Bh[s] = *(const bf16x8*)(kb  + (size_t)mm*32*Cc + s*16);
      Bl[s] = *(const bf16x8*)(klb + (size_t)mm*32*Cc + s*16);
    }
    float part = 0.f;
    #pragma unroll
    for(int jj=0;jj<2;jj++){
      f32x16 sa;
      #pragma unroll
      for(int r=0;r<16;r++) sa[r]=0.f;
      #pragma unroll
      for(int s=0;s<4;s++){
        bf16x8 Ah = *(const bf16x8*)(qb  + (size_t)jj*32*Cc + s*16);
        bf16x8 Al = *(const bf16x8*)(qlb + (size_t)jj*32*Cc + s*16);
        sa = MFMA32(Ah,Bh[s],sa);
        sa = MFMA32(Al,Bh[s],sa);
        sa = MFMA32(Ah,Bl[s],sa);
      }
      #pragma unroll
      for(int r=0;r<16;r++) part += __expf(sa[r]);
    }
    part += __shfl_down(part, 32);
    if(l<32) atomicAdd(&Z[(size_t)b*Nn + m0 + mm*32 + l], part);
  }
}

// ---------------- xzT[b][c][m] = bf16(x[b,m,c] / Z[b,m])  (plain row-major) ----------------
__global__ __launch_bounds__(256) void xzt_k(const float* __restrict__ x,
    const float* __restrict__ Z, unsigned short* __restrict__ xzT){
  __shared__ float tile[64][65];
  int b = blockIdx.y;
  int m0 = blockIdx.x*64; int t = threadIdx.x;
  for(int i=0;i<16;i++){
    int mm = i*4 + (t>>6); int cc = t&63;
    tile[mm][cc] = x[((size_t)b*Nn + m0+mm)*Cc + cc];
  }
  __syncthreads();
  for(int i=0;i<16;i++){
    int cc = i*4 + (t>>6); int mm = t&63;
    float iz = 1.0f/Z[(size_t)b*Nn + m0+mm];
    xzT[((size_t)b*Cc + cc)*Nn + m0 + mm] = f2bf(tile[mm][cc]*iz);
  }
}

// ===== fused v2: P[b,j,c] = sum_m bf16(exp(K·Q)) * xz[c,m]; E in-register =====
// grid (64 j-tiles, 8 b); block = 8 waves; wave w sweeps m in [w*256, w*256+256).
// Per-block LDS reduction (ds_add_f32) -> plain coalesced P stores. NO global atomics.
__global__ __launch_bounds__(512) void fused_k(
    const unsigned short* __restrict__ Qhi, const unsigned short* __restrict__ Qlo,
    const unsigned short* __restrict__ Khi, const unsigned short* __restrict__ Klo,
    const unsigned short* __restrict__ xzT, float* __restrict__ P){
  __shared__ float plds[32*64];
  int t = threadIdx.x, w = t>>6, l = t&63, lr = l&31, hh = l>>5;
  int b = blockIdx.y;
  int j0 = blockIdx.x*32;
  #pragma unroll
  for(int i=0;i<4;i++) plds[i*512+t]=0.f;
  __syncthreads();
  // hoisted Q B-frags (swapped: Q is the B operand, col = j = lr)
  const unsigned short* qb  = Qhi + ((size_t)b*Nn + j0 + lr)*Cc + hh*8;
  const unsigned short* qlb = Qlo + ((size_t)b*Nn + j0 + lr)*Cc + hh*8;
  bf16x8 Qh[4], Ql[4];
  #pragma unroll
  for(int s=0;s<4;s++){
    Qh[s] = *(const bf16x8*)(qb  + s*16);
    Ql[s] = *(const bf16x8*)(qlb + s*16);
  }
  const unsigned short* kb  = Khi + ((size_t)b*Nn + lr)*Cc + hh*8;
  const unsigned short* klb = Klo + ((size_t)b*Nn + lr)*Cc + hh*8;
  const unsigned short* xzb = xzT + ((size_t)b*Cc + lr)*Nn + hh*8;
  f32x16 pa0, pa1;
  #pragma unroll
  for(int r=0;r<16;r++){ pa0[r]=0.f; pa1[r]=0.f; }
  int mbase = w*256;
  #pragma unroll 2
  for(int st=0; st<8; st++){
    int m0 = mbase + st*32;
    f32x16 sa;
    #pragma unroll
    for(int r=0;r<16;r++) sa[r]=0.f;
    #pragma unroll
    for(int s=0;s<4;s++){
      bf16x8 Ah = *(const bf16x8*)(kb  + (size_t)m0*Cc + s*16);
      bf16x8 Al = *(const bf16x8*)(klb + (size_t)m0*Cc + s*16);
      sa = MFMA32(Ah, Qh[s], sa);   // Khi·Qhi
      sa = MFMA32(Al, Qh[s], sa);   // Klo·Qhi
      sa = MFMA32(Ah, Ql[s], sa);   // Khi·Qlo
    }
    // E = bf16(exp(S')); relayout C-frag -> A-frags via permlane32_swap (T12)
    unsigned wd0,wd1,wd2,wd3,wd4,wd5,wd6,wd7;
    {
      unsigned x0 = pk2(__expf(sa[0]),  __expf(sa[1]));
      unsigned x1 = pk2(__expf(sa[2]),  __expf(sa[3]));
      unsigned y0 = pk2(__expf(sa[4]),  __expf(sa[5]));
      unsigned y1 = pk2(__expf(sa[6]),  __expf(sa[7]));
      asm("v_permlane32_swap_b32 %0, %1" : "+v"(x0), "+v"(y0));
      asm("v_permlane32_swap_b32 %0, %1" : "+v"(x1), "+v"(y1));
      wd0=x0; wd1=x1; wd2=y0; wd3=y1;
      unsigned x2 = pk2(__expf(sa[8]),  __expf(sa[9]));
      unsigned x3 = pk2(__expf(sa[10]), __expf(sa[11]));
      unsigned y2 = pk2(__expf(sa[12]), __expf(sa[13]));
      unsigned y3 = pk2(__expf(sa[14]), __expf(sa[15]));
      asm("v_permlane32_swap_b32 %0, %1" : "+v"(x2), "+v"(y2));
      asm("v_permlane32_swap_b32 %0, %1" : "+v"(x3), "+v"(y3));
      wd4=x2; wd5=x3; wd6=y2; wd7=y3;
    }
    u32x4 u1 = {wd0,wd1,wd2,wd3};
    u32x4 u2 = {wd4,wd5,wd6,wd7};
    bf16x8 f1 = __builtin_bit_cast(bf16x8, u1);   // E rows j, k = m0..m0+15
    bf16x8 f2 = __builtin_bit_cast(bf16x8, u2);   // E rows j, k = m0+16..m0+31
    // xz B-frags and P MFMAs
    bf16x8 b00 = *(const bf16x8*)(xzb + m0);
    bf16x8 b01 = *(const bf16x8*)(xzb + m0 + 16);
    bf16x8 b10 = *(const bf16x8*)(xzb + (size_t)32*Nn + m0);
    bf16x8 b11 = *(const bf16x8*)(xzb + (size_t)32*Nn + m0 + 16);
    pa0 = MFMA32(f1, b00, pa0);
    pa0 = MFMA32(f2, b01, pa0);
    pa1 = MFMA32(f1, b10, pa1);
    pa1 = MFMA32(f2, b11, pa1);
  }
  // LDS reduction across the 8 waves
  #pragma unroll
  for(int r=0;r<16;r++){
    int jr = (r&3) + 8*(r>>2) + 4*hh;
    atomicAdd(&plds[jr*64 + lr],      pa0[r]);
    atomicAdd(&plds[jr*64 + 32 + lr], pa1[r]);
  }
  __syncthreads();
  // coalesced write-out: thread -> one f32x4
  {
    int row = t>>4, c0 = (t&15)*4;
    float* Pb = P + ((size_t)b*Nn + j0 + row)*Cc + c0;
    *(f32x4*)Pb = *(const f32x4*)&plds[row*64 + c0];
  }
}

// ---------------- final: dy_diag + elementwise combine ----------------
__global__ __launch_bounds__(256) void final_k(const float* __restrict__ x,
    const float* __restrict__ xt, const float* __restrict__ P,
    const float* __restrict__ WvT, const float* __restrict__ Xp,
    const float* __restrict__ r_, const float* __restrict__ diagA,
    const int* __restrict__ cnt, const int* __restrict__ idx,
    const float* __restrict__ val, const float* __restrict__ tb,
    const float* __restrict__ alp, const float* __restrict__ bet,
    float* __restrict__ out){
  int t=threadIdx.x; int l=t&63;
  int bn = blockIdx.x*4 + (t>>6);
  int b = bn>>11, n = bn&2047;
  float wv = WvT[n*Cc+l];
  float xs = 0.f;
  const float* xpb = Xp + (size_t)b*32*Cc;
  #pragma unroll 8
  for(int p=0;p<32;p++) xs += xpb[p*Cc + l];
  float tacc = r_[n]*xs;
  int cn = cnt[n];
  const float* Pb = P + (size_t)b*Nn*Cc;
  const int* ix = idx + n*CAPS;
  const float* vl = val + n*CAPS;
  for(int k=0;k<cn;k++)
    tacc += vl[k] * Pb[(size_t)ix[k]*Cc + l];
  float d = wv*tacc;
  #pragma unroll
  for(int off=32;off>=1;off>>=1) d += __shfl_xor(d,off);
  size_t g = (size_t)bn*Cc + l;
  float o = alp[0]*diagA[n]*x[g] + bet[0]*(d*xt[g] + tb[l]);
  out[g] = fmaxf(o,0.f);
}

extern "C" void kernel_launch(void* const* d_in, const int* in_sizes, int n_in,
                              void* d_out, int out_size, void* d_ws, size_t ws_size,
                              hipStream_t stream){
  const float* x  = (const float*)d_in[0];
  const float* A  = (const float*)d_in[1];
  const float* Wq = (const float*)d_in[2];
  const float* Wk = (const float*)d_in[3];
  const float* Wv = (const float*)d_in[4];
  const float* Tw = (const float*)d_in[5];
  const float* tb = (const float*)d_in[6];
  const float* alp= (const float*)d_in[7];
  const float* bet= (const float*)d_in[8];
  float* out = (float*)d_out;

  char* base = (char*)d_ws; size_t off=0;
  auto al=[&](size_t sz)->void*{ void* q = base+off; off=(off+sz+255)&~(size_t)255; return q; };
  unsigned short* Qhi=(unsigned short*)al((size_t)Bb*Nn*Cc*2);
  unsigned short* Qlo=(unsigned short*)al((size_t)Bb*Nn*Cc*2);
  unsigned short* Khi=(unsigned short*)al((size_t)Bb*Nn*Cc*2);
  unsigned short* Klo=(unsigned short*)al((size_t)Bb*Nn*Cc*2);
  float* xt  =(float*)al((size_t)Bb*Nn*Cc*4);
  float* P   =(float*)al((size_t)Bb*Nn*Cc*4);   // fully written by fused_k
  float* Z   =(float*)al((size_t)Bb*Nn*4);      // zeroed by mega_k (64 KB)
  float* Xp  =(float*)al((size_t)256*Cc*4);
  float* WvT =(float*)al((size_t)Nn*Cc*4);
  float* r_  =(float*)al((size_t)Nn*4);
  float* dgA =(float*)al((size_t)Nn*4);
  int*   cnt =(int*)al((size_t)Nn*4);
  int*   idx =(int*)al((size_t)Nn*CAPS*4);
  float* val =(float*)al((size_t)Nn*CAPS*4);
  unsigned short* xzT=(unsigned short*)al((size_t)Bb*Cc*Nn*2);
  (void)ws_size;

  mega_k<<<801, 256, 0, stream>>>(x, A, Wq, Wk, Tw, Wv,
      Qhi, Qlo, Khi, Klo, xt, Xp, r_, dgA, cnt, idx, val, WvT, (char*)Z);
  zpass_k<<<dim3(16,16,Bb), 256, 0, stream>>>(Qhi,Qlo,Khi,Klo,Z);
  xzt_k<<<dim3(32,Bb), 256, 0, stream>>>(x,Z,xzT);
  fused_k<<<dim3(64,Bb), 512, 0, stream>>>(Qhi,Qlo,Khi,Klo,xzT,P);
  final_k<<<Bb*Nn/4, 256, 0, stream>>>(x,xt,P,WvT,Xp,r_,dgA,cnt,idx,val,tb,alp,bet,out);
}

// Round 7
// 131.655 us; speedup vs baseline: 1.5370x; 1.5370x over previous
//
#include <hip/hip_runtime.h>

constexpr int Bb = 8;
constexpr int Nn = 2048;
constexpr int Cc = 64;
constexpr int CAPS = 192;

typedef __attribute__((ext_vector_type(4))) float f32x4;
typedef __attribute__((ext_vector_type(16))) float f32x16;
typedef __attribute__((ext_vector_type(8))) short bf16x8;
typedef __attribute__((ext_vector_type(4))) unsigned u32x4;

__device__ inline unsigned short f2bf(float f){
  unsigned u = __builtin_bit_cast(unsigned, f);
  unsigned r = (u + 0x7FFFu + ((u>>16)&1u)) >> 16;
  return (unsigned short)r;
}
__device__ inline float bf2f(unsigned short h){
  unsigned u = ((unsigned)h)<<16; return __builtin_bit_cast(float,u);
}
__device__ inline unsigned pk2(float a, float b){
  return (unsigned)f2bf(a) | ((unsigned)f2bf(b)<<16);
}

// frag-major layouts: 16B chunk index -> element offset (in shorts)
// Q/K: element (row j|m, c): s=row>>5, q=c>>4, l=(row&31)+32*((c>>3)&1), short c&7
__device__ inline size_t qk_chunk(int b, int s, int q, int l){
  return ((((size_t)b*64 + s)*4 + q)*64 + l)*8;
}
// xz: element (c, m): mq=m>>4, cb=c>>5, l=(c&31)+32*((m>>3)&1), short m&7
__device__ inline size_t xz_chunk(int b, int mq, int cb, int l){
  return ((((size_t)b*128 + mq)*2 + cb)*64 + l)*8;
}

#define MFMA32(a,b,c) __builtin_amdgcn_mfma_f32_32x32x16_bf16(a,b,c,0,0,0)

// ===== mega pre-kernel: prep(QK hi/lo frag-major + xt + xsum partials) | extract | WvT =====
__global__ __launch_bounds__(256) void mega_k(
    const float* __restrict__ x, const float* __restrict__ A,
    const float* __restrict__ Wq, const float* __restrict__ Wk,
    const float* __restrict__ Tw, const float* __restrict__ Wv,
    unsigned short* __restrict__ Qhi, unsigned short* __restrict__ Qlo,
    unsigned short* __restrict__ Khi, unsigned short* __restrict__ Klo,
    float* __restrict__ xt, float* __restrict__ Xp,
    float* __restrict__ r_, float* __restrict__ diagA, int* __restrict__ cnt,
    int* __restrict__ idx, float* __restrict__ val,
    float* __restrict__ WvT){
  __shared__ __attribute__((aligned(16))) char smem[65792];
  int blk = blockIdx.x; int t = threadIdx.x;

  if(blk < 256){
    // ---------------- prep ----------------
    float* wql = (float*)smem;           // 4096 f
    float* wkl = wql + 4096;
    float* twl = wkl + 4096;
    float (*xr)[64] = (float(*)[64])(twl + 4096); // [64][64]
    float* xsl = (float*)(xr + 64);      // 64 f
    #pragma unroll
    for(int i=0;i<4;i++){
      *(f32x4*)&wql[i*1024+t*4] = *(const f32x4*)&Wq[i*1024+t*4];
      *(f32x4*)&wkl[i*1024+t*4] = *(const f32x4*)&Wk[i*1024+t*4];
      *(f32x4*)&twl[i*1024+t*4] = *(const f32x4*)&Tw[i*1024+t*4];
    }
    if(t<64) xsl[t]=0.f;
    long long row0 = (long long)blk*64;
    int r = t>>4, q = t&15, c0 = q*4;
    #pragma unroll
    for(int i=0;i<4;i++){
      int row = i*16 + r;
      *(f32x4*)&xr[row][c0] = *(const f32x4*)&x[(row0+row)*Cc + c0];
    }
    __syncthreads();
    f32x4 aq[4], ak[4], at4[4];
    #pragma unroll
    for(int g=0;g<4;g++){ aq[g]=(f32x4){0,0,0,0}; ak[g]=(f32x4){0,0,0,0}; at4[g]=(f32x4){0,0,0,0}; }
    for(int kk=0;kk<64;kk++){
      f32x4 wq4 = *(const f32x4*)&wql[kk*64+c0];
      f32x4 wk4 = *(const f32x4*)&wkl[kk*64+c0];
      f32x4 wt4 = *(const f32x4*)&twl[kk*64+c0];
      #pragma unroll
      for(int g=0;g<4;g++){
        float xv = xr[g*16+r][kk];
        aq[g] += xv*wq4; ak[g] += xv*wk4; at4[g] += xv*wt4;
      }
    }
    float xsp[4] = {0.f,0.f,0.f,0.f};
    int q2 = c0>>4, hb = (c0>>3)&1, cs = c0&7;
    #pragma unroll
    for(int g=0;g<4;g++){
      #pragma unroll
      for(int d=0;d<4;d++) xsp[d] += xr[g*16+r][c0+d];
      long long rg = row0 + g*16 + r;
      unsigned long long hq=0,lq=0,hk=0,lk=0;
      #pragma unroll
      for(int d=0;d<4;d++){
        float v = aq[g][d];
        unsigned short h = f2bf(v); unsigned short lo2 = f2bf(v - bf2f(h));
        hq |= (unsigned long long)h << (16*d); lq |= (unsigned long long)lo2 << (16*d);
        v = ak[g][d];
        h = f2bf(v); lo2 = f2bf(v - bf2f(h));
        hk |= (unsigned long long)h << (16*d); lk |= (unsigned long long)lo2 << (16*d);
      }
      int b2 = (int)(rg>>11); int s2 = ((int)rg>>5)&63;
      int l2 = ((int)rg&31) + 32*hb;
      size_t off = qk_chunk(b2, s2, q2, l2) + cs;
      *(unsigned long long*)&Qhi[off] = hq;
      *(unsigned long long*)&Qlo[off] = lq;
      *(unsigned long long*)&Khi[off] = hk;
      *(unsigned long long*)&Klo[off] = lk;
      *(f32x4*)&xt[rg*Cc + c0] = at4[g];
    }
    __syncthreads();
    #pragma unroll
    for(int d=0;d<4;d++) atomicAdd(&xsl[c0+d], xsp[d]);
    __syncthreads();
    if(t<64) Xp[blk*64+t] = xsl[t];
  } else if(blk < 768){
    // ---------------- extract ----------------
    int n = (blk-256)*4 + (t>>6); int l = t&63;
    const float* row = A + (size_t)n*Nn;
    float mn = 1e30f;
    for(int j=l;j<Nn;j+=64) mn = fminf(mn, row[j]);
    #pragma unroll
    for(int off=32;off>=1;off>>=1) mn = fminf(mn, __shfl_xor(mn,off));
    float thr = mn*1.3f;
    int bse=0;
    for(int j0=0;j0<Nn;j0+=64){
      float v = row[j0+l];
      bool f = v>thr;
      unsigned long long m = __ballot(f);
      int pos = __popcll(m & ((1ull<<l)-1ull));
      if(f && bse+pos<CAPS){ idx[n*CAPS+bse+pos]=j0+l; val[n*CAPS+bse+pos]=v-mn; }
      bse += __popcll(m);
    }
    if(l==0){ r_[n]=mn; diagA[n]=row[n]; cnt[n] = bse<CAPS? bse : CAPS; }
  } else {
    // ---------------- WvT ----------------
    float (*tile)[65] = (float(*)[65])smem;
    int n0 = (blk-768)*64;
    for(int i=0;i<16;i++){
      int cc = i*4 + (t>>6); int nn2 = t&63;
      tile[cc][nn2] = Wv[(size_t)cc*Nn + n0 + nn2];
    }
    __syncthreads();
    for(int i=0;i<16;i++){
      int nn2 = i*4 + (t>>6); int cc = t&63;
      WvT[(size_t)(n0+nn2)*Cc + cc] = tile[cc][nn2];
    }
  }
}

// ===== zpass: Z[b][m] = sum_j exp(Q[b,j]·K[b,m]); block owns m-tile 32, waves split j =====
__global__ __launch_bounds__(256,2) void zpass_k(
    const unsigned short* __restrict__ Qhi, const unsigned short* __restrict__ Qlo,
    const unsigned short* __restrict__ Khi, const unsigned short* __restrict__ Klo,
    float* __restrict__ Z){
  __shared__ float Zl[32];
  int id = blockIdx.x; int b = id&7; int mt = id>>3;   // 64 m-tiles of 32
  int t = threadIdx.x, w = t>>6, l = t&63;
  if(t<32) Zl[t]=0.f;
  __syncthreads();
  bf16x8 Kh[4], Kl4[4];
  #pragma unroll
  for(int q=0;q<4;q++){
    Kh[q]  = *(const bf16x8*)(Khi + qk_chunk(b, mt, q, l));
    Kl4[q] = *(const bf16x8*)(Klo + qk_chunk(b, mt, q, l));
  }
  float zacc = 0.f;
  for(int jt=0; jt<16; jt++){
    int s = w*16 + jt;
    bf16x8 Qh4[4], Ql4[4];
    #pragma unroll
    for(int q=0;q<4;q++){
      Qh4[q] = *(const bf16x8*)(Qhi + qk_chunk(b, s, q, l));
      Ql4[q] = *(const bf16x8*)(Qlo + qk_chunk(b, s, q, l));
    }
    f32x16 sa;
    #pragma unroll
    for(int r=0;r<16;r++) sa[r]=0.f;
    #pragma unroll
    for(int q=0;q<4;q++){
      sa = MFMA32(Qh4[q], Kh[q],  sa);
      sa = MFMA32(Ql4[q], Kh[q],  sa);
      sa = MFMA32(Qh4[q], Kl4[q], sa);
    }
    float p = 0.f;
    #pragma unroll
    for(int r=0;r<16;r++) p += __expf(sa[r]);
    zacc += p;
  }
  zacc += __shfl_down(zacc, 32);
  if(l<32) atomicAdd(&Zl[l], zacc);
  __syncthreads();
  if(t<32) Z[(size_t)b*Nn + mt*32 + t] = Zl[t];
}

// ===== xzt: xzf (frag-major) = bf16(x[b,m,c] / Z[b,m]) =====
__global__ __launch_bounds__(256) void xzt_k(const float* __restrict__ x,
    const float* __restrict__ Z, unsigned short* __restrict__ xzf){
  __shared__ float tile[64][65];
  __shared__ float izl[64];
  int id = blockIdx.x; int b = id&7; int mt = id>>3;  // 32 m-tiles of 64
  int m0 = mt*64; int t = threadIdx.x;
  for(int i=0;i<16;i++){
    int mm = i*4 + (t>>6); int cc = t&63;
    tile[mm][cc] = x[((size_t)b*Nn + m0+mm)*Cc + cc];
  }
  if(t<64) izl[t] = 1.0f/Z[(size_t)b*Nn + m0 + t];
  __syncthreads();
  #pragma unroll
  for(int i=0;i<2;i++){
    int k2 = i*256 + t; int mg = k2>>6; int c = k2&63;
    int mloc = mg*8;
    unsigned u0 = pk2(tile[mloc+0][c]*izl[mloc+0], tile[mloc+1][c]*izl[mloc+1]);
    unsigned u1 = pk2(tile[mloc+2][c]*izl[mloc+2], tile[mloc+3][c]*izl[mloc+3]);
    unsigned u2 = pk2(tile[mloc+4][c]*izl[mloc+4], tile[mloc+5][c]*izl[mloc+5]);
    unsigned u3 = pk2(tile[mloc+6][c]*izl[mloc+6], tile[mloc+7][c]*izl[mloc+7]);
    u32x4 uu = {u0,u1,u2,u3};
    int mq = (m0 + mloc)>>4; int cb = c>>5; int l2 = (c&31) + 32*(mg&1);
    *(u32x4*)(xzf + xz_chunk(b, mq, cb, l2)) = uu;
  }
}

// ===== fused: P[b,j,c] = sum_m bf16(exp(K·Q)) * xz; block owns j-tile 32, waves split m =====
__global__ __launch_bounds__(256,2) void fused_k(
    const unsigned short* __restrict__ Qhi, const unsigned short* __restrict__ Qlo,
    const unsigned short* __restrict__ Khi, const unsigned short* __restrict__ Klo,
    const unsigned short* __restrict__ xzf, float* __restrict__ P){
  __shared__ float plds[32*64];
  int id = blockIdx.x; int b = id&7; int js = id>>3;  // 64 j-tiles of 32
  int t = threadIdx.x, w = t>>6, l = t&63, lr = l&31, hh = l>>5;
  #pragma unroll
  for(int i=0;i<8;i++) plds[i*256+t]=0.f;
  __syncthreads();
  // hoisted Q B-frags (swapped: Q is the B operand, col = j)
  bf16x8 Qh4[4], Ql4[4];
  #pragma unroll
  for(int q=0;q<4;q++){
    Qh4[q] = *(const bf16x8*)(Qhi + qk_chunk(b, js, q, l));
    Ql4[q] = *(const bf16x8*)(Qlo + qk_chunk(b, js, q, l));
  }
  f32x16 pa0, pa1;
  #pragma unroll
  for(int r=0;r<16;r++){ pa0[r]=0.f; pa1[r]=0.f; }
  for(int mt=0; mt<16; mt++){
    int s = w*16 + mt;          // m-sub of 32
    bf16x8 Kh4[4], Kl4[4];
    #pragma unroll
    for(int q=0;q<4;q++){
      Kh4[q] = *(const bf16x8*)(Khi + qk_chunk(b, s, q, l));
      Kl4[q] = *(const bf16x8*)(Klo + qk_chunk(b, s, q, l));
    }
    int mq = s*2;
    bf16x8 b00 = *(const bf16x8*)(xzf + xz_chunk(b, mq,   0, l));
    bf16x8 b01 = *(const bf16x8*)(xzf + xz_chunk(b, mq+1, 0, l));
    bf16x8 b10 = *(const bf16x8*)(xzf + xz_chunk(b, mq,   1, l));
    bf16x8 b11 = *(const bf16x8*)(xzf + xz_chunk(b, mq+1, 1, l));
    f32x16 sa;
    #pragma unroll
    for(int r=0;r<16;r++) sa[r]=0.f;
    #pragma unroll
    for(int q=0;q<4;q++){
      sa = MFMA32(Kh4[q], Qh4[q], sa);   // Khi·Qhi
      sa = MFMA32(Kl4[q], Qh4[q], sa);   // Klo·Qhi
      sa = MFMA32(Kh4[q], Ql4[q], sa);   // Khi·Qlo
    }
    // E = bf16(exp(S')); relayout C-frag -> A-frags via permlane32_swap (T12)
    unsigned wd0,wd1,wd2,wd3,wd4,wd5,wd6,wd7;
    {
      unsigned x0 = pk2(__expf(sa[0]),  __expf(sa[1]));
      unsigned x1 = pk2(__expf(sa[2]),  __expf(sa[3]));
      unsigned y0 = pk2(__expf(sa[4]),  __expf(sa[5]));
      unsigned y1 = pk2(__expf(sa[6]),  __expf(sa[7]));
      asm("v_permlane32_swap_b32 %0, %1" : "+v"(x0), "+v"(y0));
      asm("v_permlane32_swap_b32 %0, %1" : "+v"(x1), "+v"(y1));
      wd0=x0; wd1=x1; wd2=y0; wd3=y1;
      unsigned x2 = pk2(__expf(sa[8]),  __expf(sa[9]));
      unsigned x3 = pk2(__expf(sa[10]), __expf(sa[11]));
      unsigned y2 = pk2(__expf(sa[12]), __expf(sa[13]));
      unsigned y3 = pk2(__expf(sa[14]), __expf(sa[15]));
      asm("v_permlane32_swap_b32 %0, %1" : "+v"(x2), "+v"(y2));
      asm("v_permlane32_swap_b32 %0, %1" : "+v"(x3), "+v"(y3));
      wd4=x2; wd5=x3; wd6=y2; wd7=y3;
    }
    u32x4 u1 = {wd0,wd1,wd2,wd3};
    u32x4 u2 = {wd4,wd5,wd6,wd7};
    bf16x8 f1 = __builtin_bit_cast(bf16x8, u1);   // E rows j, k = m 0..15 of tile
    bf16x8 f2 = __builtin_bit_cast(bf16x8, u2);   // E rows j, k = m 16..31
    pa0 = MFMA32(f1, b00, pa0);
    pa0 = MFMA32(f2, b01, pa0);
    pa1 = MFMA32(f1, b10, pa1);
    pa1 = MFMA32(f2, b11, pa1);
  }
  // reduce m-quarters across waves in LDS (conflict-free: lanes consecutive)
  #pragma unroll
  for(int r=0;r<16;r++){
    int jr = (r&3) + 8*(r>>2) + 4*hh;
    atomicAdd(&plds[jr*64 + lr],      pa0[r]);
    atomicAdd(&plds[jr*64 + 32 + lr], pa1[r]);
  }
  __syncthreads();
  {
    int j = t>>3, c0 = (t&7)*8;
    float* Pb = P + ((size_t)b*Nn + js*32 + j)*Cc + c0;
    *(f32x4*)Pb     = *(const f32x4*)&plds[j*64 + c0];
    *(f32x4*)(Pb+4) = *(const f32x4*)&plds[j*64 + c0 + 4];
  }
}

// ---------------- final: dy_diag + elementwise combine ----------------
__global__ __launch_bounds__(256) void final_k(const float* __restrict__ x,
    const float* __restrict__ xt, const float* __restrict__ P,
    const float* __restrict__ WvT, const float* __restrict__ Xp,
    const float* __restrict__ r_, const float* __restrict__ diagA,
    const int* __restrict__ cnt, const int* __restrict__ idx,
    const float* __restrict__ val, const float* __restrict__ tb,
    const float* __restrict__ alp, const float* __restrict__ bet,
    float* __restrict__ out){
  int t=threadIdx.x; int l=t&63;
  int bn = blockIdx.x*4 + (t>>6);
  int b = bn>>11, n = bn&2047;
  float wv = WvT[n*Cc+l];
  float xs = 0.f;
  const float* xpb = Xp + (size_t)b*32*Cc;
  #pragma unroll 8
  for(int p=0;p<32;p++) xs += xpb[p*Cc + l];
  float tacc = r_[n]*xs;
  int cn = cnt[n];
  const float* Pb = P + (size_t)b*Nn*Cc;
  const int* ix = idx + n*CAPS;
  const float* vl = val + n*CAPS;
  for(int k=0;k<cn;k++)
    tacc += vl[k] * Pb[(size_t)ix[k]*Cc + l];
  float d = wv*tacc;
  #pragma unroll
  for(int off=32;off>=1;off>>=1) d += __shfl_xor(d,off);
  size_t g = (size_t)bn*Cc + l;
  float o = alp[0]*diagA[n]*x[g] + bet[0]*(d*xt[g] + tb[l]);
  out[g] = fmaxf(o,0.f);
}

extern "C" void kernel_launch(void* const* d_in, const int* in_sizes, int n_in,
                              void* d_out, int out_size, void* d_ws, size_t ws_size,
                              hipStream_t stream){
  const float* x  = (const float*)d_in[0];
  const float* A  = (const float*)d_in[1];
  const float* Wq = (const float*)d_in[2];
  const float* Wk = (const float*)d_in[3];
  const float* Wv = (const float*)d_in[4];
  const float* Tw = (const float*)d_in[5];
  const float* tb = (const float*)d_in[6];
  const float* alp= (const float*)d_in[7];
  const float* bet= (const float*)d_in[8];
  float* out = (float*)d_out;

  char* base = (char*)d_ws; size_t off=0;
  auto al=[&](size_t sz)->void*{ void* q = base+off; off=(off+sz+255)&~(size_t)255; return q; };
  unsigned short* Qhi=(unsigned short*)al((size_t)Bb*Nn*Cc*2);
  unsigned short* Qlo=(unsigned short*)al((size_t)Bb*Nn*Cc*2);
  unsigned short* Khi=(unsigned short*)al((size_t)Bb*Nn*Cc*2);
  unsigned short* Klo=(unsigned short*)al((size_t)Bb*Nn*Cc*2);
  float* xt  =(float*)al((size_t)Bb*Nn*Cc*4);
  float* P   =(float*)al((size_t)Bb*Nn*Cc*4);   // fully written by fused_k
  float* Z   =(float*)al((size_t)Bb*Nn*4);      // fully written by zpass_k
  float* Xp  =(float*)al((size_t)256*Cc*4);
  float* WvT =(float*)al((size_t)Nn*Cc*4);
  float* r_  =(float*)al((size_t)Nn*4);
  float* dgA =(float*)al((size_t)Nn*4);
  int*   cnt =(int*)al((size_t)Nn*4);
  int*   idx =(int*)al((size_t)Nn*CAPS*4);
  float* val =(float*)al((size_t)Nn*CAPS*4);
  unsigned short* xzf=(unsigned short*)al((size_t)Bb*Cc*Nn*2);
  (void)ws_size;

  mega_k<<<800, 256, 0, stream>>>(x, A, Wq, Wk, Tw, Wv,
      Qhi, Qlo, Khi, Klo, xt, Xp, r_, dgA, cnt, idx, val, WvT);
  zpass_k<<<512, 256, 0, stream>>>(Qhi,Qlo,Khi,Klo,Z);
  xzt_k<<<256, 256, 0, stream>>>(x,Z,xzf);
  fused_k<<<512, 256, 0, stream>>>(Qhi,Qlo,Khi,Klo,xzf,P);
  final_k<<<Bb*Nn/4, 256, 0, stream>>>(x,xt,P,WvT,Xp,r_,dgA,cnt,idx,val,tb,alp,bet,out);
}